// Round 2
// baseline (395.969 us; speedup 1.0000x reference)
//
#include <hip/hip_runtime.h>

#define B_SZ 16
#define S_SZ 8192
#define H_SZ 256

typedef _Float16 half8 __attribute__((ext_vector_type(8)));
typedef float f32x4 __attribute__((ext_vector_type(4)));

__device__ __forceinline__ float tanh_fast(float x) {
  // tanh(x) = 1 - 2/(e^{2x}+1); saturates correctly at +-inf.
  float e = __expf(2.0f * x);
  return 1.0f - 2.0f / (e + 1.0f);
}

// ---------------------------------------------------------------------------
// Phase A: qb[b,o] = dot(query[b,:], Wq[o,:]) + b_attn[o]  (qb -> ctx slot,
// consumed by fused kernel, overwritten by combine with final context).
// ---------------------------------------------------------------------------
__global__ __launch_bounds__(256) void prep_kernel(
    const float* __restrict__ query, const float* __restrict__ W_attn,
    const float* __restrict__ b_attn, float* __restrict__ qb) {
  const int b = blockIdx.x;
  const int jo = blockIdx.y;
  const int wid = threadIdx.x >> 6;
  const int lane = threadIdx.x & 63;
  const float4 q4 = *(const float4*)(query + b * H_SZ + lane * 4);
#pragma unroll 4
  for (int i = 0; i < 16; i++) {
    const int o = jo * 64 + wid * 16 + i;
    const float4 w = *(const float4*)(W_attn + (size_t)o * 512 + lane * 4);
    float p = q4.x * w.x + q4.y * w.y + q4.z * w.z + q4.w * w.w;
#pragma unroll
    for (int off = 32; off >= 1; off >>= 1) p += __shfl_xor(p, off, 64);
    if (lane == 0) qb[b * H_SZ + o] = p + b_attn[o];
  }
}

// ---------------------------------------------------------------------------
// Fused scores+softmax+context, v2. 512 blocks x 512 threads (8 waves).
// Per block: 256 key/value rows, 8 chunks of 32 rows, ONE barrier per chunk.
// Each wave owns TWO 16-o MFMA tiles (A-fragment reuse: every LDS bfrag
// feeds 2 MFMAs -> half the LDS read traffic of v1). Online softmax is
// computed REDUNDANTLY per wave from psum[c][] after the barrier (identical
// data + identical op order -> identical m in every wave); no wave0-serial
// window, no second barrier. Each chunk has a private psum buffer (zeroed
// once in the prologue) so there is no zero-reuse race. Wave 0 additionally
// keeps the running Z and writes raw scores. Value rows (4 per wave) are
// prefetched at chunk top and folded after the barrier with rescale.
// ---------------------------------------------------------------------------
__global__ __launch_bounds__(512, 4) void fused_kernel(
    const float* __restrict__ key, const float* __restrict__ value,
    const float* __restrict__ W_attn, const float* __restrict__ qb,
    const float* __restrict__ vvec, float* __restrict__ scores,
    float* __restrict__ ctxp, float* __restrict__ mblk,
    float* __restrict__ zblk) {
  __shared__ _Float16 kbuf[2][32 * 256];  // 2 x 16 KiB key staging
  __shared__ float psum[8][32];           // per-chunk score accumulators
  __shared__ float4 comb[8][64];          // epilogue combine (8 KiB)

  const int tid = threadIdx.x;
  const int wid = tid >> 6;    // wave 0..7, owns o-tiles 2*wid, 2*wid+1
  const int lane = tid & 63;
  const int n = lane & 15;     // A row (o within tile) / D column (key row)
  const int quad = lane >> 4;
  const int rowBase = blockIdx.x * 256;
  const int b = blockIdx.x >> 5;  // 32 blocks per batch

  // A fragments: Wk[o][k], o = (2*wid+ot)*16 + n, k = ks*32 + quad*8 + j.
  half8 afrag[2][8];
#pragma unroll
  for (int ot = 0; ot < 2; ot++) {
    const float* wrow =
        W_attn + (size_t)((wid * 2 + ot) * 16 + n) * 512 + 256 + quad * 8;
#pragma unroll
    for (int ks = 0; ks < 8; ks++) {
      float4 f0 = *(const float4*)(wrow + ks * 32);
      float4 f1 = *(const float4*)(wrow + ks * 32 + 4);
      half8 a;
      a[0] = (_Float16)f0.x; a[1] = (_Float16)f0.y;
      a[2] = (_Float16)f0.z; a[3] = (_Float16)f0.w;
      a[4] = (_Float16)f1.x; a[5] = (_Float16)f1.y;
      a[6] = (_Float16)f1.z; a[7] = (_Float16)f1.w;
      afrag[ot][ks] = a;
    }
  }
  // Epilogue constants: lane holds D rows m = quad*4+rg of each o-tile.
  float qbv[2][4], vvv[2][4];
#pragma unroll
  for (int ot = 0; ot < 2; ot++)
#pragma unroll
    for (int rg = 0; rg < 4; rg++) {
      const int o = (wid * 2 + ot) * 16 + quad * 4 + rg;
      qbv[ot][rg] = qb[b * H_SZ + o];
      vvv[ot][rg] = vvec[o];
    }

  if (tid < 256) ((float*)psum)[tid] = 0.f;  // all 8 chunk buffers

  // Key staging: 512 threads = 32 rows x 16 threads; 16 consecutive floats
  // (two 8-float segments s0, s0+1) per thread. XOR-swizzle per segment.
  const int srow = tid >> 4;
  const int s0 = (tid & 15) * 2;
  const size_t sbase = (size_t)(rowBase + srow) * H_SZ + (tid & 15) * 16;
  const int sd0 = srow * 256 + ((s0 ^ srow) << 3);
  const int sd1 = srow * 256 + (((s0 + 1) ^ srow) << 3);

  // Value: wave w owns rows 4w..4w+3 of each chunk; lane = float4 column.
  const float* vbase = value + (size_t)(rowBase + 4 * wid) * H_SZ + lane * 4;

  // Prologue: stage key chunk 0.
  {
    float4 f0 = *(const float4*)(key + sbase);
    float4 f1 = *(const float4*)(key + sbase + 4);
    float4 f2 = *(const float4*)(key + sbase + 8);
    float4 f3 = *(const float4*)(key + sbase + 12);
    half8 h0, h1;
    h0[0] = (_Float16)f0.x; h0[1] = (_Float16)f0.y;
    h0[2] = (_Float16)f0.z; h0[3] = (_Float16)f0.w;
    h0[4] = (_Float16)f1.x; h0[5] = (_Float16)f1.y;
    h0[6] = (_Float16)f1.z; h0[7] = (_Float16)f1.w;
    h1[0] = (_Float16)f2.x; h1[1] = (_Float16)f2.y;
    h1[2] = (_Float16)f2.z; h1[3] = (_Float16)f2.w;
    h1[4] = (_Float16)f3.x; h1[5] = (_Float16)f3.y;
    h1[6] = (_Float16)f3.z; h1[7] = (_Float16)f3.w;
    *(half8*)&kbuf[0][sd0] = h0;
    *(half8*)&kbuf[0][sd1] = h1;
  }
  __syncthreads();

  float4 acc4 = {0.f, 0.f, 0.f, 0.f};  // this wave's value accumulator
  float m_run = -1e30f;                // redundant per-wave running max
  float z_run = 0.f;                   // live only in wave 0

  for (int c = 0; c < 8; c++) {
    // Value loads for chunk c (consumed after the barrier -> hidden under
    // the MFMA phase).
    const float4 va0 = *(const float4*)(vbase + (size_t)c * 32 * H_SZ);
    const float4 va1 = *(const float4*)(vbase + (size_t)c * 32 * H_SZ + H_SZ);
    const float4 va2 =
        *(const float4*)(vbase + (size_t)c * 32 * H_SZ + 2 * H_SZ);
    const float4 va3 =
        *(const float4*)(vbase + (size_t)c * 32 * H_SZ + 3 * H_SZ);
    // Key loads for chunk c+1 (in flight during the MFMA phase).
    float4 g0, g1, g2, g3;
    if (c < 7) {
      const size_t nb = sbase + (size_t)(c + 1) * 32 * H_SZ;
      g0 = *(const float4*)(key + nb);
      g1 = *(const float4*)(key + nb + 4);
      g2 = *(const float4*)(key + nb + 8);
      g3 = *(const float4*)(key + nb + 12);
    }
    const _Float16* kb = kbuf[c & 1];
#pragma unroll
    for (int rt = 0; rt < 2; rt++) {
      const int lrow = rt * 16 + n;  // key row within chunk (D column)
      f32x4 acc0 = {0.f, 0.f, 0.f, 0.f};
      f32x4 acc1 = {0.f, 0.f, 0.f, 0.f};
#pragma unroll
      for (int ks = 0; ks < 8; ks++) {
        half8 bfrag =
            *(const half8*)&kb[lrow * 256 + (((ks * 4 + quad) ^ lrow) << 3)];
        acc0 = __builtin_amdgcn_mfma_f32_16x16x32_f16(afrag[0][ks], bfrag,
                                                      acc0, 0, 0, 0);
        acc1 = __builtin_amdgcn_mfma_f32_16x16x32_f16(afrag[1][ks], bfrag,
                                                      acc1, 0, 0, 0);
      }
      float p = 0.f;
#pragma unroll
      for (int rg = 0; rg < 4; rg++) {
        p = fmaf(vvv[0][rg], tanh_fast(qbv[0][rg] + acc0[rg]), p);
        p = fmaf(vvv[1][rg], tanh_fast(qbv[1][rg] + acc1[rg]), p);
      }
      // Sum over the 4 quads (same key row, different o-subsets).
      p += __shfl_xor(p, 16, 64);
      p += __shfl_xor(p, 32, 64);
      if (quad == 0) atomicAdd(&psum[c][lrow], p);
    }
    if (c < 7) {  // cvt + publish key chunk c+1
      half8 h0, h1;
      h0[0] = (_Float16)g0.x; h0[1] = (_Float16)g0.y;
      h0[2] = (_Float16)g0.z; h0[3] = (_Float16)g0.w;
      h0[4] = (_Float16)g1.x; h0[5] = (_Float16)g1.y;
      h0[6] = (_Float16)g1.z; h0[7] = (_Float16)g1.w;
      h1[0] = (_Float16)g2.x; h1[1] = (_Float16)g2.y;
      h1[2] = (_Float16)g2.z; h1[3] = (_Float16)g2.w;
      h1[4] = (_Float16)g3.x; h1[5] = (_Float16)g3.y;
      h1[6] = (_Float16)g3.z; h1[7] = (_Float16)g3.w;
      *(half8*)&kbuf[(c + 1) & 1][sd0] = h0;
      *(half8*)&kbuf[(c + 1) & 1][sd1] = h1;
    }
    __syncthreads();  // psum[c] complete; key chunk c+1 published.

    // Redundant per-wave online softmax (identical in every wave).
    const float sv = psum[c][lane & 31];  // lanes 0-31 distinct, 32-63 dup
    float cm = sv;
#pragma unroll
    for (int off = 16; off >= 1; off >>= 1)
      cm = fmaxf(cm, __shfl_xor(cm, off, 64));
    const float m_new = fmaxf(m_run, cm);
    const float scl = __expf(m_run - m_new);  // 0 on first chunk
    m_run = m_new;
    const float wl = __expf(sv - m_new);
    if (wid == 0) {  // raw scores + running Z (nobody waits on this)
      if (lane < 32) scores[rowBase + c * 32 + lane] = sv;
      float zc = wl;
#pragma unroll
      for (int off = 16; off >= 1; off >>= 1) zc += __shfl_xor(zc, off, 64);
      z_run = fmaf(z_run, scl, zc);
    }
    // Weights for this wave's 4 value rows (broadcast from lanes 4w..4w+3).
    const float w0 = __shfl(wl, 4 * wid + 0, 64);
    const float w1 = __shfl(wl, 4 * wid + 1, 64);
    const float w2 = __shfl(wl, 4 * wid + 2, 64);
    const float w3 = __shfl(wl, 4 * wid + 3, 64);
    acc4.x = fmaf(w3, va3.x,
             fmaf(w2, va2.x, fmaf(w1, va1.x, fmaf(w0, va0.x, acc4.x * scl))));
    acc4.y = fmaf(w3, va3.y,
             fmaf(w2, va2.y, fmaf(w1, va1.y, fmaf(w0, va0.y, acc4.y * scl))));
    acc4.z = fmaf(w3, va3.z,
             fmaf(w2, va2.z, fmaf(w1, va1.z, fmaf(w0, va0.z, acc4.z * scl))));
    acc4.w = fmaf(w3, va3.w,
             fmaf(w2, va2.w, fmaf(w1, va1.w, fmaf(w0, va0.w, acc4.w * scl))));
  }

  // Epilogue: combine 8 wave accumulators; write per-block partials.
  comb[wid][lane] = acc4;
  __syncthreads();
  if (tid < 64) {
    float4 t4 = comb[0][tid];
#pragma unroll
    for (int j = 1; j < 8; j++) {
      const float4 u = comb[j][tid];
      t4.x += u.x; t4.y += u.y; t4.z += u.z; t4.w += u.w;
    }
    *(float4*)(ctxp + (size_t)blockIdx.x * 256 + tid * 4) = t4;
  }
  if (tid == 0) {
    mblk[blockIdx.x] = m_run;
    zblk[blockIdx.x] = z_run;
  }
}

// ---------------------------------------------------------------------------
// Combine: per batch, merge the 32 block partials -> global m, Z, context;
// normalize the raw scores into attention weights in place. 16 blocks x 1024.
// ---------------------------------------------------------------------------
__global__ __launch_bounds__(1024) void combine_kernel(
    const float* __restrict__ ctxp, const float* __restrict__ mblk,
    const float* __restrict__ zblk, float* __restrict__ attn,
    float* __restrict__ ctx) {
  const int b = blockIdx.x;
  const int t = threadIdx.x;
  __shared__ float ms[32], zs[32];
  if (t < 32) {
    ms[t] = mblk[b * 32 + t];
    zs[t] = zblk[b * 32 + t];
  }
  __syncthreads();
  float m = -1e30f;
#pragma unroll
  for (int j = 0; j < 32; j++) m = fmaxf(m, ms[j]);
  float Z = 0.f;
  float e[32];  // fully unrolled -> registers (no scratch)
#pragma unroll
  for (int j = 0; j < 32; j++) {
    e[j] = __expf(ms[j] - m);
    Z = fmaf(zs[j], e[j], Z);
  }
  const float invZ = 1.0f / Z;
  if (t < 256) {
    float acc = 0.f;
#pragma unroll
    for (int j = 0; j < 32; j++)
      acc = fmaf(ctxp[(size_t)(b * 32 + j) * 256 + t], e[j], acc);
    ctx[b * H_SZ + t] = acc * invZ;
  }
  float* arow = attn + (size_t)b * S_SZ;
#pragma unroll
  for (int k = 0; k < 8; k++) {
    const int idx = k * 1024 + t;
    arow[idx] = __expf(arow[idx] - m) * invZ;
  }
}

// ---------------------------------------------------------------------------
extern "C" void kernel_launch(void* const* d_in, const int* in_sizes, int n_in,
                              void* d_out, int out_size, void* d_ws,
                              size_t ws_size, hipStream_t stream) {
  const float* query = (const float*)d_in[0];   // (16,1,256)
  const float* key = (const float*)d_in[1];     // (16,8192,256)
  const float* value = (const float*)d_in[2];   // (16,8192,256)
  const float* W_attn = (const float*)d_in[3];  // (256,512)
  const float* b_attn = (const float*)d_in[4];  // (256,)
  const float* vvec = (const float*)d_in[5];    // (256,)

  float* out = (float*)d_out;
  float* ctx = out;          // 16*256 (qb scratch, then final context)
  float* attn = out + 4096;  // 16*8192 (raw scores -> weights in place)
  float* ctxp = (float*)d_ws;            // 512*256 per-block partial contexts
  float* mblk = ctxp + 512 * 256;        // 512 per-block maxes
  float* zblk = mblk + 512;              // 512 per-block partition sums

  prep_kernel<<<dim3(B_SZ, 4), 256, 0, stream>>>(query, W_attn, b_attn, ctx);
  fused_kernel<<<512, 512, 0, stream>>>(key, value, W_attn, ctx, vvec, attn,
                                        ctxp, mblk, zblk);
  combine_kernel<<<B_SZ, 1024, 0, stream>>>(ctxp, mblk, zblk, attn, ctx);
}

// Round 5
// 311.720 us; speedup vs baseline: 1.2703x; 1.2703x over previous
//
#include <hip/hip_runtime.h>

#define B_SZ 16
#define S_SZ 8192
#define H_SZ 256

typedef _Float16 half8 __attribute__((ext_vector_type(8)));
typedef float f32x4 __attribute__((ext_vector_type(4)));

__device__ __forceinline__ float tanh_fast(float x) {
  // tanh(x) = 1 - 2/(e^{2x}+1); saturates correctly at +-inf.
  float e = __expf(2.0f * x);
  return 1.0f - 2.0f / (e + 1.0f);
}

// ---------------------------------------------------------------------------
// Phase A: qb[b,o] = dot(query[b,:], Wq[o,:]) + b_attn[o]  (qb -> ctx slot,
// consumed by fused kernel, overwritten by combine with final context).
// ---------------------------------------------------------------------------
__global__ __launch_bounds__(256) void prep_kernel(
    const float* __restrict__ query, const float* __restrict__ W_attn,
    const float* __restrict__ b_attn, float* __restrict__ qb) {
  const int b = blockIdx.x;
  const int jo = blockIdx.y;
  const int wid = threadIdx.x >> 6;
  const int lane = threadIdx.x & 63;
  const float4 q4 = *(const float4*)(query + b * H_SZ + lane * 4);
#pragma unroll 4
  for (int i = 0; i < 16; i++) {
    const int o = jo * 64 + wid * 16 + i;
    const float4 w = *(const float4*)(W_attn + (size_t)o * 512 + lane * 4);
    float p = q4.x * w.x + q4.y * w.y + q4.z * w.z + q4.w * w.w;
#pragma unroll
    for (int off = 32; off >= 1; off >>= 1) p += __shfl_xor(p, off, 64);
    if (lane == 0) qb[b * H_SZ + o] = p + b_attn[o];
  }
}

// ---------------------------------------------------------------------------
// Fused scores+softmax+context, v3b. 512 blocks x 1024 threads (16 waves).
// Round-1 register budget (one 16-o tile per wave, afrag[8] = 32 VGPR, the
// proven conflict-free 8-float/thread XOR staging) + round-2's schedule:
// ONE barrier per chunk (per-chunk psum[8][32], zeroed once in the prologue
// -> no zero-reuse race) and REDUNDANT per-wave online softmax (identical
// data + identical op order -> bitwise-identical m in all waves; nobody
// waits on wave 0). Wave 0 additionally keeps running Z and writes raw
// scores. Each wave prefetches its 2 value rows at chunk top (latency
// hidden under the MFMA phase) and folds them after the barrier with the
// online rescale. v3b: dedicated comb[] epilogue buffer (no kbuf aliasing).
// ---------------------------------------------------------------------------
__global__ __launch_bounds__(1024, 4) void fused_kernel(
    const float* __restrict__ key, const float* __restrict__ value,
    const float* __restrict__ W_attn, const float* __restrict__ qb,
    const float* __restrict__ vvec, float* __restrict__ scores,
    float* __restrict__ ctxp, float* __restrict__ mblk,
    float* __restrict__ zblk) {
  __shared__ __align__(16) _Float16 kbuf[2][32 * 256];  // 2 x 16 KiB staging
  __shared__ float psum[8][32];                         // per-chunk scores
  __shared__ float4 comb[16][64];                       // epilogue (16 KiB)

  const int tid = threadIdx.x;
  const int wid = tid >> 6;    // o-tile index, 0..15
  const int lane = tid & 63;
  const int n = lane & 15;     // A row (o within tile) / D column (key row)
  const int quad = lane >> 4;
  const int rowBase = blockIdx.x * 256;
  const int b = blockIdx.x >> 5;  // 32 blocks per batch

  // A fragments: Wk[o = wid*16 + n][k], k = ks*32 + quad*8 + j. Loaded once.
  half8 afrag[8];
  {
    const float* wrow = W_attn + (size_t)(wid * 16 + n) * 512 + 256 + quad * 8;
#pragma unroll
    for (int ks = 0; ks < 8; ks++) {
      float4 f0 = *(const float4*)(wrow + ks * 32);
      float4 f1 = *(const float4*)(wrow + ks * 32 + 4);
      half8 a;
      a[0] = (_Float16)f0.x; a[1] = (_Float16)f0.y;
      a[2] = (_Float16)f0.z; a[3] = (_Float16)f0.w;
      a[4] = (_Float16)f1.x; a[5] = (_Float16)f1.y;
      a[6] = (_Float16)f1.z; a[7] = (_Float16)f1.w;
      afrag[ks] = a;
    }
  }
  // Epilogue constants: this lane holds D rows m = quad*4+rg -> o = wid*16+m.
  float qbv[4], vvv[4];
#pragma unroll
  for (int rg = 0; rg < 4; rg++) {
    qbv[rg] = qb[b * H_SZ + wid * 16 + quad * 4 + rg];
    vvv[rg] = vvec[wid * 16 + quad * 4 + rg];
  }

  if (tid < 256) ((float*)psum)[tid] = 0.f;  // all 8 chunk buffers

  // Key staging: 1024 threads = 32 rows x 32 segs (8 f32 each), XOR-swizzled.
  const int srow = tid >> 5;
  const int sseg = tid & 31;
  const size_t sbase = (size_t)(rowBase + srow) * H_SZ + sseg * 8;
  const int sdst = srow * 256 + ((sseg ^ srow) << 3);

  // Value: wave w owns rows 2w, 2w+1 of each chunk; lane = float4 column.
  const float* vbase = value + (size_t)(rowBase + 2 * wid) * H_SZ + lane * 4;

  // Prologue: stage key chunk 0.
  {
    float4 f0 = *(const float4*)(key + sbase);
    float4 f1 = *(const float4*)(key + sbase + 4);
    half8 h;
    h[0] = (_Float16)f0.x; h[1] = (_Float16)f0.y;
    h[2] = (_Float16)f0.z; h[3] = (_Float16)f0.w;
    h[4] = (_Float16)f1.x; h[5] = (_Float16)f1.y;
    h[6] = (_Float16)f1.z; h[7] = (_Float16)f1.w;
    *(half8*)&kbuf[0][sdst] = h;
  }
  __syncthreads();

  float4 acc4 = {0.f, 0.f, 0.f, 0.f};  // this wave's value accumulator
  float m_run = -1e30f;                // redundant per-wave running max
  float z_run = 0.f;                   // meaningful only in wave 0

  for (int c = 0; c < 8; c++) {
    // Value loads for chunk c (consumed after the barrier -> latency hides
    // under the MFMA phase).
    const float4 va0 = *(const float4*)(vbase + (size_t)c * 32 * H_SZ);
    const float4 va1 = *(const float4*)(vbase + (size_t)c * 32 * H_SZ + H_SZ);
    // Key loads for chunk c+1 (in flight during the MFMA phase).
    float4 g0, g1;
    if (c < 7) {
      const size_t nb = sbase + (size_t)(c + 1) * 32 * H_SZ;
      g0 = *(const float4*)(key + nb);
      g1 = *(const float4*)(key + nb + 4);
    }
    const _Float16* kb = kbuf[c & 1];
#pragma unroll
    for (int rt = 0; rt < 2; rt++) {
      const int lrow = rt * 16 + n;  // key row within chunk (D column)
      f32x4 acc = {0.f, 0.f, 0.f, 0.f};
#pragma unroll
      for (int ks = 0; ks < 8; ks++) {
        half8 bfrag =
            *(const half8*)&kb[lrow * 256 + (((ks * 4 + quad) ^ lrow) << 3)];
        acc = __builtin_amdgcn_mfma_f32_16x16x32_f16(afrag[ks], bfrag, acc,
                                                     0, 0, 0);
      }
      float p = 0.f;
#pragma unroll
      for (int rg = 0; rg < 4; rg++)
        p = fmaf(vvv[rg], tanh_fast(qbv[rg] + acc[rg]), p);
      // Sum over the 4 quads (same key row, different o-subsets).
      p += __shfl_xor(p, 16, 64);
      p += __shfl_xor(p, 32, 64);
      if (quad == 0) atomicAdd(&psum[c][lrow], p);
    }
    if (c < 7) {  // cvt + publish key chunk c+1
      half8 h;
      h[0] = (_Float16)g0.x; h[1] = (_Float16)g0.y;
      h[2] = (_Float16)g0.z; h[3] = (_Float16)g0.w;
      h[4] = (_Float16)g1.x; h[5] = (_Float16)g1.y;
      h[6] = (_Float16)g1.z; h[7] = (_Float16)g1.w;
      *(half8*)&kbuf[(c + 1) & 1][sdst] = h;
    }
    __syncthreads();  // psum[c] complete; key chunk c+1 published.

    // Redundant per-wave online softmax. Butterfly over offsets 16..1 covers
    // all 32 distinct psum values (data is 32-periodic across the wave).
    const float sv = psum[c][lane & 31];
    float cm = sv;
#pragma unroll
    for (int off = 16; off >= 1; off >>= 1)
      cm = fmaxf(cm, __shfl_xor(cm, off, 64));
    const float m_new = fmaxf(m_run, cm);
    const float scl = __expf(m_run - m_new);  // 0 on first chunk
    m_run = m_new;
    const float wl = __expf(sv - m_new);
    if (wid == 0) {  // raw scores + running Z (nobody waits on this)
      if (lane < 32) scores[rowBase + c * 32 + lane] = sv;
      float zc = wl;
#pragma unroll
      for (int off = 16; off >= 1; off >>= 1) zc += __shfl_xor(zc, off, 64);
      z_run = fmaf(z_run, scl, zc);
    }
    // Weights for this wave's 2 value rows (broadcast from lanes 2w, 2w+1).
    const float w0 = __shfl(wl, 2 * wid + 0, 64);
    const float w1 = __shfl(wl, 2 * wid + 1, 64);
    acc4.x = fmaf(w1, va1.x, fmaf(w0, va0.x, acc4.x * scl));
    acc4.y = fmaf(w1, va1.y, fmaf(w0, va0.y, acc4.y * scl));
    acc4.z = fmaf(w1, va1.z, fmaf(w0, va0.z, acc4.z * scl));
    acc4.w = fmaf(w1, va1.w, fmaf(w0, va0.w, acc4.w * scl));
  }

  // Epilogue: combine 16 wave accumulators; write per-block partials.
  comb[wid][lane] = acc4;
  __syncthreads();
  if (tid < 64) {
    float4 t4 = comb[0][tid];
#pragma unroll
    for (int j = 1; j < 16; j++) {
      const float4 u = comb[j][tid];
      t4.x += u.x; t4.y += u.y; t4.z += u.z; t4.w += u.w;
    }
    *(float4*)(ctxp + (size_t)blockIdx.x * 256 + tid * 4) = t4;
  }
  if (tid == 0) {
    mblk[blockIdx.x] = m_run;
    zblk[blockIdx.x] = z_run;
  }
}

// ---------------------------------------------------------------------------
// Combine: per batch, merge the 32 block partials -> global m, Z, context;
// normalize the raw scores into attention weights in place. 16 blocks x 1024.
// ---------------------------------------------------------------------------
__global__ __launch_bounds__(1024) void combine_kernel(
    const float* __restrict__ ctxp, const float* __restrict__ mblk,
    const float* __restrict__ zblk, float* __restrict__ attn,
    float* __restrict__ ctx) {
  const int b = blockIdx.x;
  const int t = threadIdx.x;
  __shared__ float ms[32], zs[32];
  if (t < 32) {
    ms[t] = mblk[b * 32 + t];
    zs[t] = zblk[b * 32 + t];
  }
  __syncthreads();
  float m = -1e30f;
#pragma unroll
  for (int j = 0; j < 32; j++) m = fmaxf(m, ms[j]);
  float Z = 0.f;
  float e[32];  // fully unrolled -> registers (no scratch)
#pragma unroll
  for (int j = 0; j < 32; j++) {
    e[j] = __expf(ms[j] - m);
    Z = fmaf(zs[j], e[j], Z);
  }
  const float invZ = 1.0f / Z;
  if (t < 256) {
    float acc = 0.f;
#pragma unroll
    for (int j = 0; j < 32; j++)
      acc = fmaf(ctxp[(size_t)(b * 32 + j) * 256 + t], e[j], acc);
    ctx[b * H_SZ + t] = acc * invZ;
  }
  float* arow = attn + (size_t)b * S_SZ;
#pragma unroll
  for (int k = 0; k < 8; k++) {
    const int idx = k * 1024 + t;
    arow[idx] = __expf(arow[idx] - m) * invZ;
  }
}

// ---------------------------------------------------------------------------
extern "C" void kernel_launch(void* const* d_in, const int* in_sizes, int n_in,
                              void* d_out, int out_size, void* d_ws,
                              size_t ws_size, hipStream_t stream) {
  const float* query = (const float*)d_in[0];   // (16,1,256)
  const float* key = (const float*)d_in[1];     // (16,8192,256)
  const float* value = (const float*)d_in[2];   // (16,8192,256)
  const float* W_attn = (const float*)d_in[3];  // (256,512)
  const float* b_attn = (const float*)d_in[4];  // (256,)
  const float* vvec = (const float*)d_in[5];    // (256,)

  float* out = (float*)d_out;
  float* ctx = out;          // 16*256 (qb scratch, then final context)
  float* attn = out + 4096;  // 16*8192 (raw scores -> weights in place)
  float* ctxp = (float*)d_ws;            // 512*256 per-block partial contexts
  float* mblk = ctxp + 512 * 256;        // 512 per-block maxes
  float* zblk = mblk + 512;              // 512 per-block partition sums

  prep_kernel<<<dim3(B_SZ, 4), 256, 0, stream>>>(query, W_attn, b_attn, ctx);
  fused_kernel<<<512, 1024, 0, stream>>>(key, value, W_attn, ctx, vvec, attn,
                                         ctxp, mblk, zblk);
  combine_kernel<<<B_SZ, 1024, 0, stream>>>(ctxp, mblk, zblk, attn, ctx);
}

// Round 6
// 311.257 us; speedup vs baseline: 1.2722x; 1.0015x over previous
//
#include <hip/hip_runtime.h>

#define B_SZ 16
#define S_SZ 8192
#define H_SZ 256

typedef _Float16 half8 __attribute__((ext_vector_type(8)));
typedef float f32x4 __attribute__((ext_vector_type(4)));

// Pin a float4's registers at this program point: the load producing it must
// have issued (and, before a barrier's vmcnt(0) drain, completed) here.
#define PIN4(v) \
  asm volatile("" : "+v"((v).x), "+v"((v).y), "+v"((v).z), "+v"((v).w))

__device__ __forceinline__ float tanh_fast(float x) {
  // tanh(x) = 1 - 2/(e^{2x}+1); saturates correctly at +-inf.
  float e = __expf(2.0f * x);
  return 1.0f - 2.0f / (e + 1.0f);
}

// ---------------------------------------------------------------------------
// Phase A: qb[b,o] = dot(query[b,:], Wq[o,:]) + b_attn[o]  (qb -> ctx slot,
// consumed by fused kernel, overwritten by combine with final context).
// ---------------------------------------------------------------------------
__global__ __launch_bounds__(256) void prep_kernel(
    const float* __restrict__ query, const float* __restrict__ W_attn,
    const float* __restrict__ b_attn, float* __restrict__ qb) {
  const int b = blockIdx.x;
  const int jo = blockIdx.y;
  const int wid = threadIdx.x >> 6;
  const int lane = threadIdx.x & 63;
  const float4 q4 = *(const float4*)(query + b * H_SZ + lane * 4);
#pragma unroll 4
  for (int i = 0; i < 16; i++) {
    const int o = jo * 64 + wid * 16 + i;
    const float4 w = *(const float4*)(W_attn + (size_t)o * 512 + lane * 4);
    float p = q4.x * w.x + q4.y * w.y + q4.z * w.z + q4.w * w.w;
#pragma unroll
    for (int off = 32; off >= 1; off >>= 1) p += __shfl_xor(p, off, 64);
    if (lane == 0) qb[b * H_SZ + o] = p + b_attn[o];
  }
}

// ---------------------------------------------------------------------------
// Fused scores+softmax+context, v4. 512 blocks x 1024 threads (16 waves).
// v3b structure (one barrier/chunk, per-chunk psum, redundant per-wave
// online softmax) + REAL memory pipelining:
//  - depth-2 value prefetch: chunk c+1's value rows are loaded at the top of
//    chunk c and held in registers ACROSS the barrier; the fold of chunk c
//    uses registers loaded one full chunk earlier (zero wait at use).
//  - asm pins before the barrier stop the compiler from sinking the
//    prefetch loads past it (they are const-__restrict loads, otherwise
//    freely movable); the barrier's vmcnt(0) drain is the collection point.
//  - launch_bounds(1024,4) caps VGPR at 128 and deliberately accepts 16
//    waves/CU (1 block) so the prefetch state can stay live in registers
//    (v3b's 60-VGPR allocation had provably sunk the prefetches).
// ---------------------------------------------------------------------------
__global__ __launch_bounds__(1024, 4) void fused_kernel(
    const float* __restrict__ key, const float* __restrict__ value,
    const float* __restrict__ W_attn, const float* __restrict__ qb,
    const float* __restrict__ vvec, float* __restrict__ scores,
    float* __restrict__ ctxp, float* __restrict__ mblk,
    float* __restrict__ zblk) {
  __shared__ __align__(16) _Float16 kbuf[2][32 * 256];  // 2 x 16 KiB staging
  __shared__ float psum[8][32];                         // per-chunk scores
  __shared__ float4 comb[16][64];                       // epilogue (16 KiB)

  const int tid = threadIdx.x;
  const int wid = tid >> 6;    // o-tile index, 0..15
  const int lane = tid & 63;
  const int n = lane & 15;     // A row (o within tile) / D column (key row)
  const int quad = lane >> 4;
  const int rowBase = blockIdx.x * 256;
  const int b = blockIdx.x >> 5;  // 32 blocks per batch

  // A fragments: Wk[o = wid*16 + n][k], k = ks*32 + quad*8 + j. Loaded once.
  half8 afrag[8];
  {
    const float* wrow = W_attn + (size_t)(wid * 16 + n) * 512 + 256 + quad * 8;
#pragma unroll
    for (int ks = 0; ks < 8; ks++) {
      float4 f0 = *(const float4*)(wrow + ks * 32);
      float4 f1 = *(const float4*)(wrow + ks * 32 + 4);
      half8 a;
      a[0] = (_Float16)f0.x; a[1] = (_Float16)f0.y;
      a[2] = (_Float16)f0.z; a[3] = (_Float16)f0.w;
      a[4] = (_Float16)f1.x; a[5] = (_Float16)f1.y;
      a[6] = (_Float16)f1.z; a[7] = (_Float16)f1.w;
      afrag[ks] = a;
    }
  }
  // Epilogue constants: this lane holds D rows m = quad*4+rg -> o = wid*16+m.
  float qbv[4], vvv[4];
#pragma unroll
  for (int rg = 0; rg < 4; rg++) {
    qbv[rg] = qb[b * H_SZ + wid * 16 + quad * 4 + rg];
    vvv[rg] = vvec[wid * 16 + quad * 4 + rg];
  }

  if (tid < 256) ((float*)psum)[tid] = 0.f;  // all 8 chunk buffers

  // Key staging: 1024 threads = 32 rows x 32 segs (8 f32 each), XOR-swizzled.
  const int srow = tid >> 5;
  const int sseg = tid & 31;
  const size_t sbase = (size_t)(rowBase + srow) * H_SZ + sseg * 8;
  const int sdst = srow * 256 + ((sseg ^ srow) << 3);

  // Value: wave w owns rows 2w, 2w+1 of each chunk; lane = float4 column.
  const float* vbase = value + (size_t)(rowBase + 2 * wid) * H_SZ + lane * 4;

  // Prologue: stage key chunk 0; load value chunk 0 into registers.
  float4 vc0 = *(const float4*)(vbase);
  float4 vc1 = *(const float4*)(vbase + H_SZ);
  {
    float4 f0 = *(const float4*)(key + sbase);
    float4 f1 = *(const float4*)(key + sbase + 4);
    half8 h;
    h[0] = (_Float16)f0.x; h[1] = (_Float16)f0.y;
    h[2] = (_Float16)f0.z; h[3] = (_Float16)f0.w;
    h[4] = (_Float16)f1.x; h[5] = (_Float16)f1.y;
    h[6] = (_Float16)f1.z; h[7] = (_Float16)f1.w;
    *(half8*)&kbuf[0][sdst] = h;
  }
  __syncthreads();

  float4 acc4 = {0.f, 0.f, 0.f, 0.f};  // this wave's value accumulator
  float m_run = -1e30f;                // redundant per-wave running max
  float z_run = 0.f;                   // meaningful only in wave 0

  for (int c = 0; c < 8; c++) {
    // Prefetch chunk c+1: value rows (held across the barrier, consumed in
    // chunk c+1's fold) and key rows (published to LDS before the barrier).
    float4 vn0 = vc0, vn1 = vc1;
    float4 g0, g1;
    if (c < 7) {
      const size_t vnb = (size_t)(c + 1) * 32 * H_SZ;
      vn0 = *(const float4*)(vbase + vnb);
      vn1 = *(const float4*)(vbase + vnb + H_SZ);
      const size_t nb = sbase + (size_t)(c + 1) * 32 * H_SZ;
      g0 = *(const float4*)(key + nb);
      g1 = *(const float4*)(key + nb + 4);
    }
    const _Float16* kb = kbuf[c & 1];
#pragma unroll
    for (int rt = 0; rt < 2; rt++) {
      const int lrow = rt * 16 + n;  // key row within chunk (D column)
      f32x4 acc = {0.f, 0.f, 0.f, 0.f};
#pragma unroll
      for (int ks = 0; ks < 8; ks++) {
        half8 bfrag =
            *(const half8*)&kb[lrow * 256 + (((ks * 4 + quad) ^ lrow) << 3)];
        acc = __builtin_amdgcn_mfma_f32_16x16x32_f16(afrag[ks], bfrag, acc,
                                                     0, 0, 0);
      }
      float p = 0.f;
#pragma unroll
      for (int rg = 0; rg < 4; rg++)
        p = fmaf(vvv[rg], tanh_fast(qbv[rg] + acc[rg]), p);
      // Sum over the 4 quads (same key row, different o-subsets).
      p += __shfl_xor(p, 16, 64);
      p += __shfl_xor(p, 32, 64);
      if (quad == 0) atomicAdd(&psum[c][lrow], p);
    }
    if (c < 7) {  // cvt + publish key chunk c+1
      half8 h;
      h[0] = (_Float16)g0.x; h[1] = (_Float16)g0.y;
      h[2] = (_Float16)g0.z; h[3] = (_Float16)g0.w;
      h[4] = (_Float16)g1.x; h[5] = (_Float16)g1.y;
      h[6] = (_Float16)g1.z; h[7] = (_Float16)g1.w;
      *(half8*)&kbuf[(c + 1) & 1][sdst] = h;
      // Pin the value prefetch here: loads must not sink past the barrier.
      PIN4(vn0);
      PIN4(vn1);
    }
    __syncthreads();  // psum[c] complete; chunk c+1 key + value all landed.

    // Redundant per-wave online softmax. Butterfly over offsets 16..1 covers
    // all 32 distinct psum values (data is 32-periodic across the wave).
    const float sv = psum[c][lane & 31];
    float cm = sv;
#pragma unroll
    for (int off = 16; off >= 1; off >>= 1)
      cm = fmaxf(cm, __shfl_xor(cm, off, 64));
    const float m_new = fmaxf(m_run, cm);
    const float scl = __expf(m_run - m_new);  // 0 on first chunk
    m_run = m_new;
    const float wl = __expf(sv - m_new);
    if (wid == 0) {  // raw scores + running Z (nobody waits on this)
      if (lane < 32) scores[rowBase + c * 32 + lane] = sv;
      float zc = wl;
#pragma unroll
      for (int off = 16; off >= 1; off >>= 1) zc += __shfl_xor(zc, off, 64);
      z_run = fmaf(z_run, scl, zc);
    }
    // Weights for this wave's 2 value rows (broadcast from lanes 2w, 2w+1).
    const float w0 = __shfl(wl, 2 * wid + 0, 64);
    const float w1 = __shfl(wl, 2 * wid + 1, 64);
    // Fold chunk c's value rows: registers loaded one chunk ago, zero wait.
    acc4.x = fmaf(w1, vc1.x, fmaf(w0, vc0.x, acc4.x * scl));
    acc4.y = fmaf(w1, vc1.y, fmaf(w0, vc0.y, acc4.y * scl));
    acc4.z = fmaf(w1, vc1.z, fmaf(w0, vc0.z, acc4.z * scl));
    acc4.w = fmaf(w1, vc1.w, fmaf(w0, vc0.w, acc4.w * scl));
    vc0 = vn0;
    vc1 = vn1;
  }

  // Epilogue: combine 16 wave accumulators; write per-block partials.
  comb[wid][lane] = acc4;
  __syncthreads();
  if (tid < 64) {
    float4 t4 = comb[0][tid];
#pragma unroll
    for (int j = 1; j < 16; j++) {
      const float4 u = comb[j][tid];
      t4.x += u.x; t4.y += u.y; t4.z += u.z; t4.w += u.w;
    }
    *(float4*)(ctxp + (size_t)blockIdx.x * 256 + tid * 4) = t4;
  }
  if (tid == 0) {
    mblk[blockIdx.x] = m_run;
    zblk[blockIdx.x] = z_run;
  }
}

// ---------------------------------------------------------------------------
// Combine: per batch, merge the 32 block partials -> global m, Z, context;
// normalize the raw scores into attention weights in place. 16 blocks x 1024.
// ---------------------------------------------------------------------------
__global__ __launch_bounds__(1024) void combine_kernel(
    const float* __restrict__ ctxp, const float* __restrict__ mblk,
    const float* __restrict__ zblk, float* __restrict__ attn,
    float* __restrict__ ctx) {
  const int b = blockIdx.x;
  const int t = threadIdx.x;
  __shared__ float ms[32], zs[32];
  if (t < 32) {
    ms[t] = mblk[b * 32 + t];
    zs[t] = zblk[b * 32 + t];
  }
  __syncthreads();
  float m = -1e30f;
#pragma unroll
  for (int j = 0; j < 32; j++) m = fmaxf(m, ms[j]);
  float Z = 0.f;
  float e[32];  // fully unrolled -> registers (no scratch)
#pragma unroll
  for (int j = 0; j < 32; j++) {
    e[j] = __expf(ms[j] - m);
    Z = fmaf(zs[j], e[j], Z);
  }
  const float invZ = 1.0f / Z;
  if (t < 256) {
    float acc = 0.f;
#pragma unroll
    for (int j = 0; j < 32; j++)
      acc = fmaf(ctxp[(size_t)(b * 32 + j) * 256 + t], e[j], acc);
    ctx[b * H_SZ + t] = acc * invZ;
  }
  float* arow = attn + (size_t)b * S_SZ;
#pragma unroll
  for (int k = 0; k < 8; k++) {
    const int idx = k * 1024 + t;
    arow[idx] = __expf(arow[idx] - m) * invZ;
  }
}

// ---------------------------------------------------------------------------
extern "C" void kernel_launch(void* const* d_in, const int* in_sizes, int n_in,
                              void* d_out, int out_size, void* d_ws,
                              size_t ws_size, hipStream_t stream) {
  const float* query = (const float*)d_in[0];   // (16,1,256)
  const float* key = (const float*)d_in[1];     // (16,8192,256)
  const float* value = (const float*)d_in[2];   // (16,8192,256)
  const float* W_attn = (const float*)d_in[3];  // (256,512)
  const float* b_attn = (const float*)d_in[4];  // (256,)
  const float* vvec = (const float*)d_in[5];    // (256,)

  float* out = (float*)d_out;
  float* ctx = out;          // 16*256 (qb scratch, then final context)
  float* attn = out + 4096;  // 16*8192 (raw scores -> weights in place)
  float* ctxp = (float*)d_ws;            // 512*256 per-block partial contexts
  float* mblk = ctxp + 512 * 256;        // 512 per-block maxes
  float* zblk = mblk + 512;              // 512 per-block partition sums

  prep_kernel<<<dim3(B_SZ, 4), 256, 0, stream>>>(query, W_attn, b_attn, ctx);
  fused_kernel<<<512, 1024, 0, stream>>>(key, value, W_attn, ctx, vvec, attn,
                                         ctxp, mblk, zblk);
  combine_kernel<<<B_SZ, 1024, 0, stream>>>(ctxp, mblk, zblk, attn, ctx);
}